// Round 6
// baseline (536.182 us; speedup 1.0000x reference)
//
#include <hip/hip_runtime.h>

// SepConv: out[b,c,i,j] = sum_{u,v} img[b,c,i+u,j+v] * vert[b,u,i,j] * hori[b,v,i,j]
// B=8, C=3, W=H=512, K=13, Wo=Ho=500.
//
// R12: T3-minimum 2-phase pipeline over output rows. Evidence trail:
//  - R6 (114.7us, 2.07 TB/s): stage 52KB -> vmcnt(0)+barrier -> compute.
//    Burst-then-drain duty cycle: 52KB in flight during stage, ZERO during
//    compute. The drain convoys all 6 waves with nothing to overlap.
//  - R8/R10/R11 (TLP designs): 1.2-1.5 TB/s. Resident waves x rotation
//    depth never reaches the ~9KB/CU Little's-law requirement, and the
//    allocator sinks any register-resident read-only weight array (R10).
//  - R7/R9 (spilling designs) accidentally proved the memory system
//    sustains 3.3-3.6 TB/s with this access mix.
// Fix: block owns RPB=4 consecutive rows, double-buffered weight LDS
// (2x52KB = 104KB -> 1 block/CU BY DESIGN). Per row r:
//    STAGE(buf[(r+1)&1], row r+1)   // fire-and-forget global_load_lds
//    sched_barrier(0)               // pin: DMA issued before compute
//    COMPUTE(buf[r&1], row r)       // R6's proven VGPR-52 body, unchanged
//    __syncthreads()                // vmcnt(0)+barrier: residual only --
//                                   // stage had the whole compute to land
// During every compute phase the CU holds 52KB of weight DMA in flight
// (5x the 9KB requirement) from 6 waves, zero extra registers. Steady
// state = max(DMA 2.1us, compute ~1.8us) per row -> BW-bound.
// Occupancy ~15-20% is BY DESIGN (in-flight bytes come from the DMA
// stream, not TLP).

#define KK 13
#define NB 8
#define NC 3
#define IW 512
#define IH 512
#define WO 500
#define HO 500
#define QROW 125              // float4 quads per 500-col row
#define NT 384                // 128 j-lanes x 3 channels
#define RPB 4                 // output rows per block
#define NQ1 (KK * QROW)       // 1625 quads per weight array per row
#define NQ2 (2 * NQ1)         // 3250: vert [0,1625) | hori [1625,3250)

typedef __attribute__((address_space(1))) const void g_void;
typedef __attribute__((address_space(3))) void l_void;

__device__ __forceinline__ void stage_row(const float4* __restrict__ vrow,
                                          const float4* __restrict__ hrow,
                                          float4* dst, int tid, size_t rs4)
{
    #pragma unroll
    for (int f0 = 0; f0 < NQ2; f0 += NT) {
        const int f = f0 + tid;
        if (f < NQ2) {
            // branchless vert/hori select: single DMA call site
            const bool is_v = (f < NQ1);
            const int g = is_v ? f : f - NQ1;
            const float4* base = is_v ? vrow : hrow;
            const unsigned u = (unsigned)g / QROW;
            const unsigned q = (unsigned)g - u * QROW;
            __builtin_amdgcn_global_load_lds(
                (g_void*)(base + (size_t)u * rs4 + q),
                (l_void*)&dst[f], 16, 0, 0);
        }
    }
}

__global__ __launch_bounds__(NT) void sepconv_kernel(
    const float* __restrict__ img,
    const float* __restrict__ hori,
    const float* __restrict__ vert,
    float* __restrict__ out)
{
    __shared__ float4 s_w[2][NQ2];   // 2 x 52000 B = 104000 B -> 1 block/CU

    const int tid = threadIdx.y * 128 + threadIdx.x;
    const int i0 = blockIdx.x * RPB;     // first output row of this block
    const int b  = blockIdx.y;           // batch

    const size_t khw = (size_t)WO * HO;  // 250000
    const size_t rs4 = khw / 4;          // 62500 float4 between k-slices
    const float4* vb0 = (const float4*)(vert + (size_t)b * KK * khw);
    const float4* hb0 = (const float4*)(hori + (size_t)b * KK * khw);

    // ---- prologue: stage row i0 into buf0, full drain (once per block) ----
    stage_row(vb0 + (size_t)i0 * QROW, hb0 + (size_t)i0 * QROW,
              s_w[0], tid, rs4);
    __syncthreads();

    const int tj = threadIdx.x;     // j-quad
    const int c  = threadIdx.y;     // channel
    const bool active = (tj < QROW);
    const int j0 = tj * 4;

    for (int r = 0; r < RPB; ++r) {
        // ---- phase 1: fire-and-forget stage of NEXT row into other buf ----
        if (r + 1 < RPB) {
            const int in = i0 + r + 1;
            stage_row(vb0 + (size_t)in * QROW, hb0 + (size_t)in * QROW,
                      s_w[(r + 1) & 1], tid, rs4);
        }
        // pin issue order: DMAs must be in flight before compute starts
        __builtin_amdgcn_sched_barrier(0);

        // ---- phase 2: compute row i0+r from current buffer (R6 body) ----
        const float4* wb = s_w[r & 1];
        if (active) {
            const int i = i0 + r;
            const float* ibase = img + (((size_t)(b * NC + c) * IW) + i) * IH + j0;

            float tmp[4][KK];
            #pragma unroll
            for (int jq = 0; jq < 4; ++jq)
                #pragma unroll
                for (int v = 0; v < KK; ++v)
                    tmp[jq][v] = 0.0f;

            // img pipeline prologue: row u = 0
            float4 c0 = *(const float4*)(ibase + 0);
            float4 c1 = *(const float4*)(ibase + 4);
            float4 c2 = *(const float4*)(ibase + 8);
            float4 c3 = *(const float4*)(ibase + 12);

            #pragma unroll
            for (int u = 0; u < KK; ++u) {
                // issue next img row before this iteration's FMAs
                float4 n0, n1, n2, n3;
                if (u < KK - 1) {
                    const float* rp = ibase + (size_t)(u + 1) * IH;
                    n0 = *(const float4*)(rp + 0);
                    n1 = *(const float4*)(rp + 4);
                    n2 = *(const float4*)(rp + 8);
                    n3 = *(const float4*)(rp + 12);
                }

                const float4 vt = wb[u * QROW + tj];   // ds_read_b128

                float row[16];
                row[0]  = c0.x; row[1]  = c0.y; row[2]  = c0.z; row[3]  = c0.w;
                row[4]  = c1.x; row[5]  = c1.y; row[6]  = c1.z; row[7]  = c1.w;
                row[8]  = c2.x; row[9]  = c2.y; row[10] = c2.z; row[11] = c2.w;
                row[12] = c3.x; row[13] = c3.y; row[14] = c3.z; row[15] = c3.w;

                #pragma unroll
                for (int v = 0; v < KK; ++v) {
                    tmp[0][v] += row[0 + v] * vt.x;
                    tmp[1][v] += row[1 + v] * vt.y;
                    tmp[2][v] += row[2 + v] * vt.z;
                    tmp[3][v] += row[3 + v] * vt.w;
                }

                if (u < KK - 1) {
                    c0 = n0; c1 = n1; c2 = n2; c3 = n3;
                }
            }

            // epilogue: fold hori from LDS
            float4 o = make_float4(0.f, 0.f, 0.f, 0.f);
            #pragma unroll
            for (int v = 0; v < KK; ++v) {
                const float4 hv = wb[NQ1 + v * QROW + tj];
                o.x += tmp[0][v] * hv.x;
                o.y += tmp[1][v] * hv.y;
                o.z += tmp[2][v] * hv.z;
                o.w += tmp[3][v] * hv.w;
            }

            float* op = out + (((size_t)(b * NC + c) * WO) + (size_t)(i0 + r)) * HO + j0;
            *(float4*)op = o;
        }

        // ---- one barrier per row: drains the residual of stage(r+1)
        // (which had the whole compute phase to land) + guards LDS reuse.
        __syncthreads();
    }
}

extern "C" void kernel_launch(void* const* d_in, const int* in_sizes, int n_in,
                              void* d_out, int out_size, void* d_ws, size_t ws_size,
                              hipStream_t stream) {
    const float* img  = (const float*)d_in[0];
    const float* hori = (const float*)d_in[1];
    const float* vert = (const float*)d_in[2];
    float* out = (float*)d_out;

    dim3 block(128, 3, 1);            // x = j-quads (125 used), y = channel
    dim3 grid(WO / RPB, NB, 1);       // 125 row-groups x 8 batches
    hipLaunchKernelGGL(sepconv_kernel, grid, block, 0, stream, img, hori, vert, out);
}

// Round 7
// 339.127 us; speedup vs baseline: 1.5811x; 1.5811x over previous
//
#include <hip/hip_runtime.h>

// SepConv: out[b,c,i,j] = sum_{u,v} img[b,c,i+u,j+v] * vert[b,u,i,j] * hori[b,v,i,j]
// B=8, C=3, W=H=512, K=13, Wo=Ho=500.
//
// R13: R6 (114.7us baseline) with ONE variable changed: weight staging via
// regular float4 loads + ds_write_b128 (HK reg-staging) instead of
// global_load_lds DMA.
// Why (6-round evidence):
//  - R6 sustained 2.07 TB/s with 3 blocks x 52KB of DMA posted per CU ->
//    only ~3KB/CU actually in flight (Little's law @375ns). Consistent
//    with a shallow per-wave LDS-DMA queue (~10-12 outstanding reqs).
//    At that cap NO gload_lds schedule can beat ~2-3.8 TB/s -- which is
//    exactly where R6/R12 landed.
//  - Only the (accidentally) spilling kernels R7/R9 ever reached 3.3-3.6
//    TB/s: scratch traffic uses the NORMAL vector-load path, which
//    supports ~63 outstanding loads/wave.
//  - R10 showed read-only weight arrays get sunk by the allocator, but
//    load->ds_write pairs are store-fed and short-lived: un-sinkable and
//    register-cheap (40 transient VGPRs, disjoint from tmp's live range
//    in this single-row structure).
// Everything else is R6 verbatim: block(128,3), grid(500,8), 52KB single
// buffer, stage -> __syncthreads -> tmp[4][13] compute with depth-1 img
// rotation -> hori epilogue.
// Per-wave in-flight during stage: 10 x 16B x 64 lanes ~ 10KB (3x the
// whole CU's previous in-flight). Stage time ~52KB @ fair-share BW ~2us
// instead of ~19us.

#define KK 13
#define NB 8
#define NC 3
#define IW 512
#define IH 512
#define WO 500
#define HO 500
#define QROW 125              // float4 quads per 500-col row
#define NT 384                // 128 j-lanes x 3 channels
#define NQ (KK * QROW)        // 1625 float4s per weight array
#define NSTEP 5               // ceil(1625/384)

__global__ __launch_bounds__(NT) void sepconv_kernel(
    const float* __restrict__ img,
    const float* __restrict__ hori,
    const float* __restrict__ vert,
    float* __restrict__ out)
{
    __shared__ float4 s_vert[NQ];   // [u][quad], 26000 B
    __shared__ float4 s_hori[NQ];   // [v][quad], 26000 B

    const int tid = threadIdx.y * 128 + threadIdx.x;
    const int i = blockIdx.x;       // output row
    const int b = blockIdx.y;       // batch

    const size_t khw = (size_t)WO * HO;      // 250000
    const size_t rs4 = khw / 4;              // 62500 float4 between k-slices
    const float4* vsrc = (const float4*)(vert + (size_t)b * KK * khw + (size_t)i * HO);
    const float4* hsrc = (const float4*)(hori + (size_t)b * KK * khw + (size_t)i * HO);

    // ---- stage weights: deep-queue vector loads, then LDS writes ----
    // Phase A: issue all 10 independent global_load_dwordx4 (static-indexed
    // arrays -> registers, store-fed so un-sinkable). ~10KB/wave in flight.
    float4 stg_v[NSTEP], stg_h[NSTEP];
    #pragma unroll
    for (int s = 0; s < NSTEP; ++s) {
        const int f = s * NT + tid;
        if (f < NQ) {
            const unsigned u = (unsigned)f / QROW;
            const unsigned q = (unsigned)f - u * QROW;
            stg_v[s] = vsrc[(size_t)u * rs4 + q];
            stg_h[s] = hsrc[(size_t)u * rs4 + q];
        }
    }
    // Phase B: drain to LDS (compiler inserts descending vmcnt waits).
    #pragma unroll
    for (int s = 0; s < NSTEP; ++s) {
        const int f = s * NT + tid;
        if (f < NQ) {
            s_vert[f] = stg_v[s];
            s_hori[f] = stg_h[s];
        }
    }
    __syncthreads();

    const int tj = threadIdx.x;     // j-quad
    const int c  = threadIdx.y;     // channel
    if (tj >= QROW) return;
    const int j0 = tj * 4;

    const float* ibase = img + (((size_t)(b * NC + c) * IW) + i) * IH + j0;

    float tmp[4][KK];
    #pragma unroll
    for (int jq = 0; jq < 4; ++jq)
        #pragma unroll
        for (int v = 0; v < KK; ++v)
            tmp[jq][v] = 0.0f;

    // ---- pipeline prologue: img row u = 0 ----
    float4 c0 = *(const float4*)(ibase + 0);
    float4 c1 = *(const float4*)(ibase + 4);
    float4 c2 = *(const float4*)(ibase + 8);
    float4 c3 = *(const float4*)(ibase + 12);

    #pragma unroll
    for (int u = 0; u < KK; ++u) {
        // issue next img row before this iteration's FMAs
        float4 n0, n1, n2, n3;
        if (u < KK - 1) {
            const float* rp = ibase + (size_t)(u + 1) * IH;
            n0 = *(const float4*)(rp + 0);
            n1 = *(const float4*)(rp + 4);
            n2 = *(const float4*)(rp + 8);
            n3 = *(const float4*)(rp + 12);
        }

        const float4 vt = s_vert[u * QROW + tj];   // ds_read_b128

        float row[16];
        row[0]  = c0.x; row[1]  = c0.y; row[2]  = c0.z; row[3]  = c0.w;
        row[4]  = c1.x; row[5]  = c1.y; row[6]  = c1.z; row[7]  = c1.w;
        row[8]  = c2.x; row[9]  = c2.y; row[10] = c2.z; row[11] = c2.w;
        row[12] = c3.x; row[13] = c3.y; row[14] = c3.z; row[15] = c3.w;

        #pragma unroll
        for (int v = 0; v < KK; ++v) {
            tmp[0][v] += row[0 + v] * vt.x;
            tmp[1][v] += row[1 + v] * vt.y;
            tmp[2][v] += row[2 + v] * vt.z;
            tmp[3][v] += row[3 + v] * vt.w;
        }

        if (u < KK - 1) {
            c0 = n0; c1 = n1; c2 = n2; c3 = n3;
        }
    }

    // ---- epilogue: fold hori from LDS ----
    float4 o = make_float4(0.f, 0.f, 0.f, 0.f);
    #pragma unroll
    for (int v = 0; v < KK; ++v) {
        const float4 hv = s_hori[v * QROW + tj];
        o.x += tmp[0][v] * hv.x;
        o.y += tmp[1][v] * hv.y;
        o.z += tmp[2][v] * hv.z;
        o.w += tmp[3][v] * hv.w;
    }

    float* op = out + (((size_t)(b * NC + c) * WO) + i) * HO + j0;
    *(float4*)op = o;
}

extern "C" void kernel_launch(void* const* d_in, const int* in_sizes, int n_in,
                              void* d_out, int out_size, void* d_ws, size_t ws_size,
                              hipStream_t stream) {
    const float* img  = (const float*)d_in[0];
    const float* hori = (const float*)d_in[1];
    const float* vert = (const float*)d_in[2];
    float* out = (float*)d_out;

    dim3 block(128, 3, 1);        // x = j-quads (125 used), y = channel
    dim3 grid(WO, NB, 1);         // x = output row i, y = batch
    hipLaunchKernelGGL(sepconv_kernel, grid, block, 0, stream, img, hori, vert, out);
}